// Round 5
// baseline (738.310 us; speedup 1.0000x reference)
//
#include <hip/hip_runtime.h>
#include <stdint.h>

#define T_SEQ 500
#define D_IN  32
#define H_DIM 64
#define BDIM  512

using short8  = __attribute__((ext_vector_type(8))) short;  // 8 bf16
using float4_ = __attribute__((ext_vector_type(4))) float;  // MFMA C/D frag

#define MFMA16(a,b,c) __builtin_amdgcn_mfma_f32_16x16x32_bf16((a),(b),(c),0,0,0)

// ---------------- LDS geometry (bytes) ----------------
// frag block = 16 rows x 16B + 16B pad
#define G_STRIDE   272
#define KT_STRIDE  (4*G_STRIDE)          // 1088
#define HL_STRIDE  (2*KT_STRIDE + 32)    // 2208  (+32: de-alias hi vs lo writes, 8 banks apart)
#define BUF_STRIDE (2*HL_STRIDE)         // 4416
#define HOFF(buf,hl,kt,g) ((buf)*BUF_STRIDE + (hl)*HL_STRIDE + (kt)*KT_STRIDE + (g)*G_STRIDE)
#define X_BASE     (2*BUF_STRIDE)        // 8832
#define XSL_STRIDE (2*KT_STRIDE)         // 2176 (hl stride 1088 == 16-bank offset, already ok)
#define XOFF(slot,hl,g) (X_BASE + (slot)*XSL_STRIDE + (hl)*KT_STRIDE + (g)*G_STRIDE)
#define LDS_BYTES  (X_BASE + 2*XSL_STRIDE)   // 13184

// ---------------- workspace layout (bytes) ----------------
#define WS_ENC   0                                // [kt3][w8][tl2][hl2][lane64] short8
#define WS_DEC0  (WS_ENC  + 3*8*2*2*64*16)        // 98304
#define WS_COMB  (WS_DEC0 + 2*8*2*2*64*16)        // 163840
#define WS_OUT   (WS_COMB + 2*8*2*2*64*16)        // 229376 : [kt2][tl2][hl2][lane64]
#define WS_BENC  (WS_OUT  + 2*2*2*64*16)          // 237568 : [w8][tl2][lane64] f32
#define WS_BDEC0 (WS_BENC  + 8*2*64*4)            // 241664
#define WS_BCOMB (WS_BDEC0 + 8*2*64*4)            // 245760
#define WS_BOUT  (WS_BCOMB + 8*2*64*4)            // 249856 : [tl2][lane64] f32

// gate scale folded into weights: i,f,o -> -log2(e); g -> +2*log2(e)
#define S_SIG  (-1.4426950408889634f)
#define S_TANH ( 2.8853900817779268f)

__device__ __forceinline__ void split_bf16(float v, unsigned short &hi, unsigned short &lo) {
    unsigned int b = __float_as_uint(v);
    hi = (unsigned short)(b >> 16);
    float vh = __uint_as_float(b & 0xFFFF0000u);
    lo = (unsigned short)(__float_as_uint(v - vh) >> 16);
}

// LDS-only barrier: order LDS writes/reads across waves WITHOUT draining vmcnt —
// x-prefetch loads and out-stores stay in flight across steps.
__device__ __forceinline__ void lds_barrier() {
    __builtin_amdgcn_sched_barrier(0);
    asm volatile("s_waitcnt lgkmcnt(0)" ::: "memory");
    __builtin_amdgcn_s_barrier();
    __builtin_amdgcn_sched_barrier(0);
}

// ==================== prep kernel: split weights into B-fragments ====================
// col mapping within wave w: tile tl, col c(0..15): gate = tl*2 + (c>>3), unit = w*8 + (c&7)
// frag element j of lane: k = (lane>>4)*8 + j  (same k-map as A side)
__global__ void __launch_bounds__(512)
prep_kernel(const float* __restrict__ Wih_e, const float* __restrict__ Whh_e,
            const float* __restrict__ b_e,
            const float* __restrict__ Wih_d, const float* __restrict__ Whh_d,
            const float* __restrict__ b_d,
            const float* __restrict__ Wout, const float* __restrict__ bout,
            char* __restrict__ ws)
{
    const int tid  = blockIdx.x * blockDim.x + threadIdx.x;
    const int nthr = gridDim.x * blockDim.x;

    // encoder gate fragments: slots (kt3, w8, tl2, lane64)  [s: lane 5:0 | tl 6 | w 9:7 | kt 11:10]
    for (int s = tid; s < 3*8*2*64; s += nthr) {
        const int lane = s & 63, tl = (s >> 6) & 1, w = (s >> 7) & 7, kt = s >> 10;
        const int c = lane & 15, rg = lane >> 4;
        const int gate = tl*2 + (c >> 3);
        const int unit = w*8 + (c & 7);
        const int n = gate*64 + unit;
        const float sc = (gate == 2) ? S_TANH : S_SIG;
        short8 hi8, lo8;
        #pragma unroll
        for (int j = 0; j < 8; ++j) {
            const int k = kt*32 + rg*8 + j;
            const float wv = sc * ((k < 32) ? Wih_e[n*D_IN + k] : Whh_e[n*H_DIM + k - 32]);
            unsigned short h_, l_; split_bf16(wv, h_, l_);
            hi8[j] = (short)h_; lo8[j] = (short)l_;
        }
        const size_t base = (size_t)((((kt*8+w)*2+tl)*2+0)*64 + lane) * 16;
        *(short8*)(ws + WS_ENC + base)           = hi8;
        *(short8*)(ws + WS_ENC + base + 64*16)   = lo8;
    }

    // decoder step-0 (Whh_d) and combined (Whh_d + Wih_d@Wout): slots (kt2, w8, tl2, lane64)
    // [s: lane 5:0 | tl 6 | w 9:7 | kt 10]
    for (int s = tid; s < 2*8*2*64; s += nthr) {
        const int lane = s & 63, tl = (s >> 6) & 1, w = (s >> 7) & 7, kt = s >> 10;
        const int c = lane & 15, rg = lane >> 4;
        const int gate = tl*2 + (c >> 3);
        const int unit = w*8 + (c & 7);
        const int n = gate*64 + unit;
        const float sc = (gate == 2) ? S_TANH : S_SIG;
        short8 h0v, l0v, hcv, lcv;
        #pragma unroll
        for (int j = 0; j < 8; ++j) {
            const int k = kt*32 + rg*8 + j;
            const float w0 = Whh_d[n*H_DIM + k];
            float a = w0;
            for (int d = 0; d < 32; ++d) a += Wih_d[n*D_IN + d] * Wout[d*H_DIM + k];
            unsigned short h_, l_;
            split_bf16(sc * w0, h_, l_); h0v[j] = (short)h_; l0v[j] = (short)l_;
            split_bf16(sc * a,  h_, l_); hcv[j] = (short)h_; lcv[j] = (short)l_;
        }
        const size_t base = (size_t)((((kt*8+w)*2+tl)*2+0)*64 + lane) * 16;
        *(short8*)(ws + WS_DEC0 + base)         = h0v;
        *(short8*)(ws + WS_DEC0 + base + 64*16) = l0v;
        *(short8*)(ws + WS_COMB + base)         = hcv;
        *(short8*)(ws + WS_COMB + base + 64*16) = lcv;
    }

    // Wout fragments: slots (kt2, tl2, lane64); col = tl*16 + (lane&15)
    for (int s = tid; s < 2*2*64; s += nthr) {
        const int lane = s & 63, tl = (s >> 6) & 1, kt = s >> 7;
        const int rg = lane >> 4;
        const int ocol = tl*16 + (lane & 15);
        short8 hi8, lo8;
        #pragma unroll
        for (int j = 0; j < 8; ++j) {
            const int k = kt*32 + rg*8 + j;
            unsigned short h_, l_; split_bf16(Wout[ocol*H_DIM + k], h_, l_);
            hi8[j] = (short)h_; lo8[j] = (short)l_;
        }
        const size_t base = (size_t)(((kt*2+tl)*2+0)*64 + lane) * 16;
        *(short8*)(ws + WS_OUT + base)         = hi8;
        *(short8*)(ws + WS_OUT + base + 64*16) = lo8;
    }

    // biases: slots (w8, tl2, lane64)
    for (int s = tid; s < 8*2*64; s += nthr) {
        const int lane = s & 63, tl = (s >> 6) & 1, w = s >> 7;
        const int c = lane & 15;
        const int gate = tl*2 + (c >> 3);
        const int unit = w*8 + (c & 7);
        const int n = gate*64 + unit;
        const float sc = (gate == 2) ? S_TANH : S_SIG;
        float a = b_d[n];
        for (int d = 0; d < 32; ++d) a += Wih_d[n*D_IN + d] * bout[d];
        ((float*)(ws + WS_BENC))[s]  = sc * b_e[n];
        ((float*)(ws + WS_BDEC0))[s] = sc * b_d[n];
        ((float*)(ws + WS_BCOMB))[s] = sc * a;
    }
    for (int s = tid; s < 2*64; s += nthr)
        ((float*)(ws + WS_BOUT))[s] = bout[(s >> 6)*16 + (s & 15)];
}

// ==================== main kernel ====================
extern "C" __global__ void __launch_bounds__(BDIM, 2)
seq2seq_main(const float* __restrict__ x, const char* __restrict__ ws,
             float* __restrict__ out)
{
    __shared__ __align__(16) char lds[LDS_BYTES];

    const int tid  = threadIdx.x;
    const int w    = tid >> 6;
    const int lane = tid & 63;
    const int rg   = lane >> 4;
    const int lcol = lane & 15;
    const int sel  = lcol >> 3;            // 0: owns i/g, rows rg*4+{0,1}; 1: owns f/o, rows rg*4+{2,3}
    const int row0 = blockIdx.x * 16;

    const int KT_H = w >> 2, G_H = w & 3, JH = lcol & 7;   // h[unit=w*8+(lcol&7)] position
    const int xr = tid >> 5, xk = tid & 31, xg = xk >> 3, xj = xk & 7;

    // ---- encoder weight fragments + biases ----
    short8 whi[3][2], wlo[3][2];
    float  bias[2];
    #pragma unroll
    for (int kt = 0; kt < 3; ++kt)
        #pragma unroll
        for (int tl = 0; tl < 2; ++tl) {
            const size_t base = (size_t)((((kt*8+w)*2+tl)*2+0)*64 + lane) * 16;
            whi[kt][tl] = *(const short8*)(ws + WS_ENC + base);
            wlo[kt][tl] = *(const short8*)(ws + WS_ENC + base + 64*16);
        }
    #pragma unroll
    for (int tl = 0; tl < 2; ++tl)
        bias[tl] = ((const float*)(ws + WS_BENC))[(w*2+tl)*64 + lane];

    float c2[2] = {0.f, 0.f};

    // zero h buf0 (both hl planes, buf 0)
    for (int i = tid; i < BUF_STRIDE/4; i += BDIM) ((uint32_t*)lds)[i] = 0u;

    // stage x[0], prefetch x[1]
    {
        const float v0 = x[((size_t)(row0 + xr)*T_SEQ + 0)*D_IN + xk];
        unsigned short h_, l_; split_bf16(v0, h_, l_);
        *(unsigned short*)(lds + XOFF(0,0,xg) + xr*16 + xj*2) = h_;
        *(unsigned short*)(lds + XOFF(0,1,xg) + xr*16 + xj*2) = l_;
    }
    float xreg = x[((size_t)(row0 + xr)*T_SEQ + 1)*D_IN + xk];
    lds_barrier();

    auto swz = [](float v) {   // lane ^ 8 exchange (in-wave)
        return __int_as_float(__builtin_amdgcn_ds_swizzle(__float_as_int(v), 0x201F));
    };

    // exchange + pointwise + h-write (2 rows per lane); 4 swizzles/step (send-side select)
    auto pw = [&](float4_ a0, float4_ a1, int nxt) {
        #pragma unroll
        for (int si = 0; si < 2; ++si) {
            // send what the partner needs: sel=0 sends a[2+si] (partner's i/g), sel=1 sends a[si] (partner's f/o)
            const float s0 = sel ? a0[si] : a0[2+si];
            const float s1 = sel ? a1[si] : a1[2+si];
            const float r0 = swz(s0);
            const float r1 = swz(s1);
            const float ip = sel ? r0        : a0[si];
            const float fp = sel ? a0[2+si]  : r0;
            const float gp = sel ? r1        : a1[si];
            const float op = sel ? a1[2+si]  : r1;
            const float ia = __builtin_amdgcn_rcpf(1.0f + __builtin_amdgcn_exp2f(ip));
            const float fa = __builtin_amdgcn_rcpf(1.0f + __builtin_amdgcn_exp2f(fp));
            const float ga = __builtin_fmaf(-2.0f,
                              __builtin_amdgcn_rcpf(1.0f + __builtin_amdgcn_exp2f(gp)), 1.0f);
            const float oa = __builtin_amdgcn_rcpf(1.0f + __builtin_amdgcn_exp2f(op));
            const float cv = __builtin_fmaf(fa, c2[si], ia * ga);
            c2[si] = cv;
            const float tt = __builtin_amdgcn_exp2f(cv * -2.8853900817779268f);
            const float hv = __builtin_fmaf(2.0f * oa,
                              __builtin_amdgcn_rcpf(1.0f + tt), -oa);
            unsigned short hh_, ll_; split_bf16(hv, hh_, ll_);
            const int rb = (rg*4 + sel*2 + si)*16 + JH*2;
            *(unsigned short*)(lds + HOFF(nxt,0,KT_H,G_H) + rb) = hh_;
            *(unsigned short*)(lds + HOFF(nxt,1,KT_H,G_H) + rb) = ll_;
        }
    };

    auto ldh = [&](int buf, int hl, int kt) {
        return *(const short8*)(lds + HOFF(buf,hl,kt,rg) + lcol*16);
    };

    // ---------------- encoder: 500 steps ----------------
    auto enc_step = [&](int CUR, int t) {
        const int NXT = CUR ^ 1;
        const short8 axh = *(const short8*)(lds + XOFF(CUR,0,rg) + lcol*16);
        const short8 axl = *(const short8*)(lds + XOFF(CUR,1,rg) + lcol*16);
        const short8 ah0 = ldh(CUR,0,0), ah1 = ldh(CUR,0,1);
        const short8 al0 = ldh(CUR,1,0), al1 = ldh(CUR,1,1);

        const float xold = xreg;
        xreg = (t + 2 < T_SEQ) ? x[((size_t)(row0 + xr)*T_SEQ + (t+2))*D_IN + xk] : 0.f;
        if (t + 1 < T_SEQ) {
            unsigned short h_, l_; split_bf16(xold, h_, l_);
            *(unsigned short*)(lds + XOFF(NXT,0,xg) + xr*16 + xj*2) = h_;
            *(unsigned short*)(lds + XOFF(NXT,1,xg) + xr*16 + xj*2) = l_;
        }

        float4_ acc[2];
        #pragma unroll
        for (int tl = 0; tl < 2; ++tl) {
            float4_ m = {bias[tl], bias[tl], bias[tl], bias[tl]};
            m = MFMA16(axh, whi[0][tl], m);
            m = MFMA16(ah0, whi[1][tl], m);
            m = MFMA16(ah1, whi[2][tl], m);
            float4_ rw = {0.f, 0.f, 0.f, 0.f};
            rw = MFMA16(axh, wlo[0][tl], rw);
            rw = MFMA16(ah0, wlo[1][tl], rw);
            rw = MFMA16(ah1, wlo[2][tl], rw);
            float4_ ra = {0.f, 0.f, 0.f, 0.f};
            ra = MFMA16(axl, whi[0][tl], ra);
            ra = MFMA16(al0, whi[1][tl], ra);
            ra = MFMA16(al1, whi[2][tl], ra);
            acc[tl] = (m + rw) + ra;
        }
        pw(acc[0], acc[1], NXT);
        lds_barrier();
    };

    int t = 0;
    for (int it = 0; it < 250; ++it) { enc_step(0, t); ++t; enc_step(1, t); ++t; }
    // h_enc now in buf 0

    // ---------------- decoder step 0 (input = zeros; Whh_d only) ----------------
    #pragma unroll
    for (int kt = 0; kt < 2; ++kt)
        #pragma unroll
        for (int tl = 0; tl < 2; ++tl) {
            const size_t base = (size_t)((((kt*8+w)*2+tl)*2+0)*64 + lane) * 16;
            whi[kt][tl] = *(const short8*)(ws + WS_DEC0 + base);
            wlo[kt][tl] = *(const short8*)(ws + WS_DEC0 + base + 64*16);
        }
    #pragma unroll
    for (int tl = 0; tl < 2; ++tl)
        bias[tl] = ((const float*)(ws + WS_BDEC0))[(w*2+tl)*64 + lane];
    {
        const short8 a0 = ldh(0,0,0), a1 = ldh(0,0,1);
        const short8 q0 = ldh(0,1,0), q1 = ldh(0,1,1);
        float4_ acc[2];
        #pragma unroll
        for (int tl = 0; tl < 2; ++tl) {
            float4_ m = {bias[tl], bias[tl], bias[tl], bias[tl]};
            m = MFMA16(a0, whi[0][tl], m);
            m = MFMA16(a1, whi[1][tl], m);
            float4_ rw = {0.f, 0.f, 0.f, 0.f};
            rw = MFMA16(a0, wlo[0][tl], rw);
            rw = MFMA16(a1, wlo[1][tl], rw);
            float4_ ra = {0.f, 0.f, 0.f, 0.f};
            ra = MFMA16(q0, whi[0][tl], ra);
            ra = MFMA16(q1, whi[1][tl], ra);
            acc[tl] = (m + rw) + ra;
        }
        pw(acc[0], acc[1], 1);
        lds_barrier();
    }

    // ---------------- decoder steps 1..499 (Wcomb; out as side-effect) ----------------
    #pragma unroll
    for (int kt = 0; kt < 2; ++kt)
        #pragma unroll
        for (int tl = 0; tl < 2; ++tl) {
            const size_t base = (size_t)((((kt*8+w)*2+tl)*2+0)*64 + lane) * 16;
            whi[kt][tl] = *(const short8*)(ws + WS_COMB + base);
            wlo[kt][tl] = *(const short8*)(ws + WS_COMB + base + 64*16);
        }
    #pragma unroll
    for (int tl = 0; tl < 2; ++tl)
        bias[tl] = ((const float*)(ws + WS_BCOMB))[(w*2+tl)*64 + lane];

    const bool ow  = (w == 0) || (w == 5);   // two out-waves on DIFFERENT SIMDs
    const int  tlo = (w == 0) ? 0 : 1;
    const int  ocol = tlo*16 + lcol;
    short8 woh[2] = {}, wol[2] = {};
    float  bo = 0.f;
    if (ow) {
        #pragma unroll
        for (int kt = 0; kt < 2; ++kt) {
            const size_t base = (size_t)(((kt*2+tlo)*2+0)*64 + lane) * 16;
            woh[kt] = *(const short8*)(ws + WS_OUT + base);
            wol[kt] = *(const short8*)(ws + WS_OUT + base + 64*16);
        }
        bo = ((const float*)(ws + WS_BOUT))[tlo*64 + lane];
    }

    auto dec_step = [&](int CUR, int s) {
        const short8 a0 = ldh(CUR,0,0), a1 = ldh(CUR,0,1);
        const short8 q0 = ldh(CUR,1,0), q1 = ldh(CUR,1,1);
        float4_ acc[2];
        #pragma unroll
        for (int tl = 0; tl < 2; ++tl) {
            float4_ m = {bias[tl], bias[tl], bias[tl], bias[tl]};
            m = MFMA16(a0, whi[0][tl], m);
            m = MFMA16(a1, whi[1][tl], m);
            float4_ rw = {0.f, 0.f, 0.f, 0.f};
            rw = MFMA16(a0, wlo[0][tl], rw);
            rw = MFMA16(a1, wlo[1][tl], rw);
            float4_ ra = {0.f, 0.f, 0.f, 0.f};
            ra = MFMA16(q0, whi[0][tl], ra);
            ra = MFMA16(q1, whi[1][tl], ra);
            acc[tl] = (m + rw) + ra;
        }
        if (ow) {   // out_{s-1} = h_s @ Wout^T + bout (stores fly async across the raw barrier)
            float4_ om = {bo, bo, bo, bo};
            om = MFMA16(a0, woh[0], om);
            om = MFMA16(a1, woh[1], om);
            float4_ o1 = {0.f, 0.f, 0.f, 0.f};
            o1 = MFMA16(a0, wol[0], o1);
            o1 = MFMA16(a1, wol[1], o1);
            float4_ o2 = {0.f, 0.f, 0.f, 0.f};
            o2 = MFMA16(q0, woh[0], o2);
            o2 = MFMA16(q1, woh[1], o2);
            const float4_ ov = (om + o1) + o2;
            #pragma unroll
            for (int r = 0; r < 4; ++r)
                out[((size_t)(row0 + rg*4 + r)*T_SEQ + (s-1))*D_IN + ocol] = ov[r];
        }
        pw(acc[0], acc[1], CUR ^ 1);
        lds_barrier();
    };

    int s = 1;
    for (int it = 0; it < 249; ++it) { dec_step(1, s); ++s; dec_step(0, s); ++s; }
    dec_step(1, s);   // s = 499; writes h_500 into buf 0

    // tail: out_499 = h_500 @ Wout^T + bout
    if (ow) {
        const short8 a0 = ldh(0,0,0), a1 = ldh(0,0,1);
        const short8 q0 = ldh(0,1,0), q1 = ldh(0,1,1);
        float4_ om = {bo, bo, bo, bo};
        om = MFMA16(a0, woh[0], om);
        om = MFMA16(a1, woh[1], om);
        float4_ o1 = {0.f, 0.f, 0.f, 0.f};
        o1 = MFMA16(a0, wol[0], o1);
        o1 = MFMA16(a1, wol[1], o1);
        float4_ o2 = {0.f, 0.f, 0.f, 0.f};
        o2 = MFMA16(q0, woh[0], o2);
        o2 = MFMA16(q1, woh[1], o2);
        const float4_ ov = (om + o1) + o2;
        #pragma unroll
        for (int r = 0; r < 4; ++r)
            out[((size_t)(row0 + rg*4 + r)*T_SEQ + (T_SEQ-1))*D_IN + ocol] = ov[r];
    }
}

extern "C" void kernel_launch(void* const* d_in, const int* in_sizes, int n_in,
                              void* d_out, int out_size, void* d_ws, size_t ws_size,
                              hipStream_t stream) {
    (void)n_in; (void)ws_size; (void)out_size;
    const float* x     = (const float*)d_in[0];
    const float* Wih_e = (const float*)d_in[1];
    const float* Whh_e = (const float*)d_in[2];
    const float* b_e   = (const float*)d_in[3];
    const float* Wih_d = (const float*)d_in[4];
    const float* Whh_d = (const float*)d_in[5];
    const float* b_d   = (const float*)d_in[6];
    const float* Wout  = (const float*)d_in[7];
    const float* bout  = (const float*)d_in[8];
    float* out = (float*)d_out;

    const int B = in_sizes[0] / (T_SEQ * D_IN);   // 4096

    hipLaunchKernelGGL(prep_kernel, dim3(8), dim3(512), 0, stream,
                       Wih_e, Whh_e, b_e, Wih_d, Whh_d, b_d, Wout, bout, (char*)d_ws);
    hipLaunchKernelGGL(seq2seq_main, dim3(B / 16), dim3(BDIM), 0, stream,
                       x, (const char*)d_ws, out);
}